// Round 14
// baseline (368.693 us; speedup 1.0000x reference)
//
#include <hip/hip_runtime.h>
#include <math.h>

#define NB 32
#define NS 8192
#define NC 64
#define NM 16
#define NL 4
#define NM2 32                 // 2*M (cos,sin interleaved)
#define TPOS 128               // positions per tile
#define NT (NS/TPOS)           // 64 tiles per batch
#define APAD 68                // bf16 h-tile row stride (2-way banks, 8B align)
#define GPAD 132               // bf16 gT row stride (2-way banks, 8B align)

typedef float f16v  __attribute__((ext_vector_type(16)));
typedef float f4v   __attribute__((ext_vector_type(4)));
typedef short bf16x8 __attribute__((ext_vector_type(8)));
typedef short bf16x4 __attribute__((ext_vector_type(4)));

#define MFMA16(a,b,c) __builtin_amdgcn_mfma_f32_16x16x32_bf16(a,b,c,0,0,0)

static __device__ __forceinline__ unsigned short f2bf(float x) {
    unsigned u = __float_as_uint(x);
    u += 0x7FFFu + ((u >> 16) & 1u);          // round-to-nearest-even
    return (unsigned short)(u >> 16);
}
static __device__ __forceinline__ float bf2f(unsigned short b) {
    return __uint_as_float(((unsigned)b) << 16);
}
static __device__ __forceinline__ bf16x8 ld8l(const unsigned short* p) {
    bf16x4 a = *(const bf16x4*)p;
    bf16x4 b = *(const bf16x4*)(p + 4);
    return __builtin_shufflevector(a, b, 0, 1, 2, 3, 4, 5, 6, 7);
}
static __device__ __forceinline__ float gelu_exact(float v) {
    return 0.5f * v * (1.0f + erff(v * 0.7071067811865475f));
}

// Trig tables: T fp32 [s][32] (k_xdft); Thi/Tlo bf16 [s][32] (spectral A);
// TThi/TTlo bf16 [32][s] (DFT B).
__global__ void k_table(float* __restrict__ T,
                        unsigned short* __restrict__ Thi,
                        unsigned short* __restrict__ Tlo,
                        unsigned short* __restrict__ TThi,
                        unsigned short* __restrict__ TTlo) {
    int s = blockIdx.x * 256 + threadIdx.x;
    if (s >= NS) return;
    const float w = 6.283185307179586f / (float)NS;
    #pragma unroll
    for (int m = 0; m < NM; ++m) {
        int idx = (m * s) & (NS - 1);
        float sv, cv;
        sincosf(w * (float)idx, &sv, &cv);
        T[(size_t)s*NM2 + 2*m]   = cv;
        T[(size_t)s*NM2 + 2*m+1] = sv;
        unsigned short ch = f2bf(cv), cl = f2bf(cv - bf2f(f2bf(cv)));
        unsigned short sh = f2bf(sv), sl = f2bf(sv - bf2f(f2bf(sv)));
        Thi[(size_t)s*NM2 + 2*m]   = ch;  Tlo[(size_t)s*NM2 + 2*m]   = cl;
        Thi[(size_t)s*NM2 + 2*m+1] = sh;  Tlo[(size_t)s*NM2 + 2*m+1] = sl;
        TThi[(size_t)(2*m)*NS + s]   = ch;  TTlo[(size_t)(2*m)*NS + s]   = cl;
        TThi[(size_t)(2*m+1)*NS + s] = sh;  TTlo[(size_t)(2*m+1)*NS + s] = sl;
    }
}

// bf16 hi/lo splits: Wl_w [l][o][i] and d1_w [o][i] (both i-contiguous B-frags)
__global__ void k_prep(const float* __restrict__ Ww, const float* __restrict__ d1w,
                       unsigned short* __restrict__ Wbhi,
                       unsigned short* __restrict__ Wblo,
                       unsigned short* __restrict__ d1hi,
                       unsigned short* __restrict__ d1lo) {
    int idx = blockIdx.x * 256 + threadIdx.x;
    if (idx < NL*NC*NC) {
        float v = Ww[idx];
        unsigned short hi = f2bf(v);
        Wbhi[idx] = hi;
        Wblo[idx] = f2bf(v - bf2f(hi));
    } else if (idx < NL*NC*NC + NC*NC) {
        int r = idx - NL*NC*NC;
        float v = d1w[r];
        unsigned short hi = f2bf(v);
        d1hi[r] = hi;
        d1lo[r] = f2bf(v - bf2f(hi));
    }
}

// X[b][k] = sum_s x[b,s] * T[s][k]  (layer-0 forward DFT, rank-1 collapse)
__global__ void __launch_bounds__(512) k_xdft(const float* __restrict__ x,
                                              const float* __restrict__ T,
                                              float* __restrict__ X) {
    __shared__ float red[16 * NM2];
    int b = blockIdx.x, t = threadIdx.x;
    int k = t & 31, sg = t >> 5;           // sg 0..15
    float acc = 0.f;
    #pragma unroll 4
    for (int it = 0; it < NS/16; ++it) {
        int s = sg * (NS/16) + it;
        acc = fmaf(x[(size_t)b*NS + s], T[(size_t)s*NM2 + k], acc);
    }
    red[sg*NM2 + k] = acc;
    __syncthreads();
    if (t < NM2) {
        float s = 0.f;
        #pragma unroll
        for (int q = 0; q < 16; ++q) s += red[q*NM2 + t];
        X[(size_t)b*NM2 + t] = s;
    }
}

// xf (k-major) -> complex R mix -> bf16 hi/lo ysbT[b][o][k]. grid (NB,4).
// l==0: xf from rank-1 analytic form (full-period trig sums vanish for m>0).
__global__ void __launch_bounds__(256) k_mix(const float* __restrict__ partial,
                                             const float* __restrict__ Rre,
                                             const float* __restrict__ Rim,
                                             const float* __restrict__ X,
                                             const float* __restrict__ ew,
                                             const float* __restrict__ eb,
                                             unsigned short* __restrict__ ysbThi,
                                             unsigned short* __restrict__ ysbTlo,
                                             int l) {
    __shared__ float xf[8 * NC];   // [kk][c], k = 8*jg + kk
    int b = blockIdx.x, jg = blockIdx.y, t = threadIdx.x;
    #pragma unroll
    for (int e = 0; e < 2; ++e) {
        int idx = t + 256*e;               // kk*64 + c
        int kk = idx >> 6, c = idx & 63;
        int k = 8*jg + kk;
        float s;
        if (l == 0) {
            s = ew[c] * X[(size_t)b*NM2 + k] + (k == 0 ? eb[c] * (float)NS : 0.f);
        } else {
            const float* pp = partial + (size_t)b*NT*NC*NM2 + (size_t)k*NC + c;
            s = 0.f;
            #pragma unroll 8
            for (int tile = 0; tile < NT; ++tile)
                s += pp[(size_t)tile * NC * NM2];
        }
        xf[kk*NC + c] = s;
    }
    __syncthreads();
    {
        int o = t >> 2, mq = t & 3;
        int m = 4*jg + mq;
        float yre = 0.f, yim = 0.f;
        #pragma unroll 8
        for (int i = 0; i < NC; ++i) {
            float xr = xf[(2*mq)*NC + i];
            float xs = xf[(2*mq+1)*NC + i];
            size_t ridx = (((size_t)l*NC + i)*NC + o)*NM + m;
            float rr = Rre[ridx], ri = Rim[ridx];
            yre = fmaf(xr, rr, yre); yre = fmaf(xs, ri, yre);
            yim = fmaf(xr, ri, yim); yim = fmaf(-xs, rr, yim);
        }
        float v0, v1;
        if (m == 0) { v0 = yre * (1.0f/NS); v1 = 0.f; }
        else        { v0 = yre * (2.0f/NS); v1 = -yim * (2.0f/NS); }
        size_t yb = ((size_t)b*NC + o)*NM2;
        unsigned short h0 = f2bf(v0);
        ysbThi[yb + 2*m]   = h0;  ysbTlo[yb + 2*m]   = f2bf(v0 - bf2f(h0));
        unsigned short h1 = f2bf(v1);
        ysbThi[yb + 2*m+1] = h1;  ysbTlo[yb + 2*m+1] = f2bf(v1 - bf2f(h1));
    }
}

// Fused spectral + dense + GELU via split-bf16 MFMA; then next-layer DFT
// (MFMA, !LAST) or decoder (MFMA d1 + shfl-reduced d2 dot, LAST).
// FIRST: A-frags built from x analytically (h = x*ew + eb), no h read.
// h stored packed: uint32 = (bf16hi<<16)|bf16lo.
template<bool FIRST, bool LAST>
__global__ void __launch_bounds__(512) k_spec(const float* __restrict__ x,
                                              unsigned* __restrict__ hpk,
                                              const unsigned short* __restrict__ Thi,
                                              const unsigned short* __restrict__ Tlo,
                                              const unsigned short* __restrict__ TThi,
                                              const unsigned short* __restrict__ TTlo,
                                              const unsigned short* __restrict__ ysbThi,
                                              const unsigned short* __restrict__ ysbTlo,
                                              const unsigned short* __restrict__ Wbhi,
                                              const unsigned short* __restrict__ Wblo,
                                              const float* __restrict__ Wlb,
                                              const unsigned short* __restrict__ d1hi,
                                              const unsigned short* __restrict__ d1lo,
                                              const float* __restrict__ d1b,
                                              const float* __restrict__ d2w,
                                              const float* __restrict__ d2b,
                                              const float* __restrict__ ew,
                                              const float* __restrict__ eb,
                                              float* __restrict__ partial,
                                              float* __restrict__ outp,
                                              int l) {
    __shared__ __align__(16) unsigned short uLDS[2 * TPOS * APAD];  // 34816 B
    unsigned short* hsAhi = uLDS;
    unsigned short* hsAlo = uLDS + TPOS * APAD;

    int tile = blockIdx.x, b = blockIdx.y;
    int t = threadIdx.x;
    int lane = t & 63, w = t >> 6;
    int lm = lane & 15, g = lane >> 4;
    int s0 = tile * TPOS;

    // --- stage h -> bf16 hi/lo LDS tile [pos][APAD] ---
    if (FIRST) {
        #pragma unroll
        for (int j = 0; j < 4; ++j) {
            int idx = t + 512*j;
            int pos = idx >> 4, q4 = (idx & 15) * 4;
            float xv = x[(size_t)b*NS + s0 + pos];
            f4v w4 = *(const f4v*)(ew + q4);
            f4v b4 = *(const f4v*)(eb + q4);
            bf16x4 hi4, lo4;
            #pragma unroll
            for (int e = 0; e < 4; ++e) {
                float v = fmaf(xv, w4[e], b4[e]);
                unsigned short hh = f2bf(v);
                hi4[e] = (short)hh;
                lo4[e] = (short)f2bf(v - bf2f(hh));
            }
            *(bf16x4*)(&hsAhi[pos*APAD + q4]) = hi4;
            *(bf16x4*)(&hsAlo[pos*APAD + q4]) = lo4;
        }
    } else {
        const uint4* hblk = (const uint4*)(hpk + ((size_t)b*NS + s0)*NC);
        #pragma unroll
        for (int j = 0; j < 4; ++j) {
            uint4 v = hblk[t + 512*j];
            int idx = t + 512*j;
            int pos = idx >> 4, q4 = (idx & 15) * 4;
            unsigned vv[4] = {v.x, v.y, v.z, v.w};
            bf16x4 hi4, lo4;
            #pragma unroll
            for (int e = 0; e < 4; ++e) {
                hi4[e] = (short)(vv[e] >> 16);
                lo4[e] = (short)(vv[e] & 0xFFFFu);
            }
            *(bf16x4*)(&hsAhi[pos*APAD + q4]) = hi4;
            *(bf16x4*)(&hsAlo[pos*APAD + q4]) = lo4;
        }
    }
    __syncthreads();

    // --- A-frags ---
    bf16x8 aHi[2], aLo[2];
    #pragma unroll
    for (int k2 = 0; k2 < 2; ++k2) {
        int eo = (w*16 + lm)*APAD + k2*32 + 8*g;
        aHi[k2] = ld8l(&hsAhi[eo]);
        aLo[k2] = ld8l(&hsAlo[eo]);
    }
    bf16x8 tHi = *(const bf16x8*)(Thi + (size_t)(s0 + w*16 + lm)*NM2 + 8*g);
    bf16x8 tLo = *(const bf16x8*)(Tlo + (size_t)(s0 + w*16 + lm)*NM2 + 8*g);

    // --- accumulators: bias broadcast ---
    f4v acc[4];
    #pragma unroll
    for (int N = 0; N < 4; ++N) {
        float bv = Wlb[(size_t)l*NC + N*16 + lm];
        acc[N] = (f4v){bv, bv, bv, bv};
    }

    // --- spectral GEMM: T(128x32) @ ysT(32x64) ---
    #pragma unroll
    for (int N = 0; N < 4; ++N) {
        size_t yo = ((size_t)b*NC + N*16 + lm)*NM2 + 8*g;
        bf16x8 yHi = *(const bf16x8*)(ysbThi + yo);
        bf16x8 yLo = *(const bf16x8*)(ysbTlo + yo);
        acc[N] = MFMA16(tHi, yHi, acc[N]);
        acc[N] = MFMA16(tHi, yLo, acc[N]);
        acc[N] = MFMA16(tLo, yHi, acc[N]);
    }

    // --- dense GEMM: h(128x64) @ W^T(64x64) ---
    #pragma unroll
    for (int k2 = 0; k2 < 2; ++k2) {
        #pragma unroll
        for (int N = 0; N < 4; ++N) {
            size_t wo = ((size_t)l*NC + N*16 + lm)*NC + k2*32 + 8*g;
            bf16x8 wHi = *(const bf16x8*)(Wbhi + wo);
            bf16x8 wLo = *(const bf16x8*)(Wblo + wo);
            acc[N] = MFMA16(aHi[k2], wHi, acc[N]);
            acc[N] = MFMA16(aHi[k2], wLo, acc[N]);
            acc[N] = MFMA16(aLo[k2], wHi, acc[N]);
        }
    }

    // --- GELU (D layout: pos = w*16 + g*4 + r, o = N*16 + lm) ---
    f4v gv[4];
    #pragma unroll
    for (int N = 0; N < 4; ++N)
        #pragma unroll
        for (int r = 0; r < 4; ++r)
            gv[N][r] = gelu_exact(acc[N][r]);

    __syncthreads();   // all hsA reads done -> safe to overlay

    if (!LAST) {
        // gT bf16 hi/lo [c][GPAD] overlay + packed-h global write
        unsigned short* gThi = uLDS;
        unsigned short* gTlo = uLDS + NC * GPAD;
        #pragma unroll
        for (int N = 0; N < 4; ++N) {
            int c = N*16 + lm;
            #pragma unroll
            for (int r = 0; r < 4; ++r) {
                int pos = w*16 + g*4 + r;
                float v = gv[N][r];
                unsigned short hh = f2bf(v);
                unsigned short ll = f2bf(v - bf2f(hh));
                gThi[c*GPAD + pos] = hh;
                gTlo[c*GPAD + pos] = ll;
                hpk[((size_t)b*NS + s0 + pos)*NC + c] =
                    ((unsigned)hh << 16) | (unsigned)ll;
            }
        }
        __syncthreads();

        // DFT GEMM: gT(64x128) @ T(128x32); k-major coalesced f4v store
        int Mblk = w & 3, Nblk = w >> 2;
        f4v pacc = {0.f, 0.f, 0.f, 0.f};
        #pragma unroll
        for (int ks = 0; ks < 4; ++ks) {
            int eo = (Mblk*16 + lm)*GPAD + ks*32 + 8*g;
            bf16x8 gHi = ld8l(&gThi[eo]);
            bf16x8 gLo = ld8l(&gTlo[eo]);
            size_t to = (size_t)(Nblk*16 + lm)*NS + s0 + ks*32 + 8*g;
            bf16x8 tbHi = *(const bf16x8*)(TThi + to);
            bf16x8 tbLo = *(const bf16x8*)(TTlo + to);
            pacc = MFMA16(gHi, tbHi, pacc);
            pacc = MFMA16(gHi, tbLo, pacc);
            pacc = MFMA16(gLo, tbHi, pacc);
        }
        // partial[b][tile][k][c], one 16B store per lane
        float* pout = partial + ((size_t)b*NT + tile)*NC*NM2;
        int k = Nblk*16 + lm;
        *(f4v*)(pout + (size_t)k*NC + Mblk*16 + g*4) = pacc;
    } else {
        // write g bf16 hi/lo pos-major (same layout as staging)
        #pragma unroll
        for (int N = 0; N < 4; ++N) {
            int c = N*16 + lm;
            #pragma unroll
            for (int r = 0; r < 4; ++r) {
                int pos = w*16 + g*4 + r;
                float v = gv[N][r];
                unsigned short hh = f2bf(v);
                hsAhi[pos*APAD + c] = hh;
                hsAlo[pos*APAD + c] = f2bf(v - bf2f(hh));
            }
        }
        __syncthreads();

        // decoder GEMM: g(128x64) @ d1^T(64x64)
        bf16x8 gH[2], gL[2];
        #pragma unroll
        for (int k2 = 0; k2 < 2; ++k2) {
            int eo = (w*16 + lm)*APAD + k2*32 + 8*g;
            gH[k2] = ld8l(&hsAhi[eo]);
            gL[k2] = ld8l(&hsAlo[eo]);
        }
        f4v a2[4];
        #pragma unroll
        for (int N = 0; N < 4; ++N) {
            float bv = d1b[N*16 + lm];
            a2[N] = (f4v){bv, bv, bv, bv};
        }
        #pragma unroll
        for (int k2 = 0; k2 < 2; ++k2) {
            #pragma unroll
            for (int N = 0; N < 4; ++N) {
                size_t wo = ((size_t)(N*16 + lm))*NC + k2*32 + 8*g;
                bf16x8 wHi = *(const bf16x8*)(d1hi + wo);
                bf16x8 wLo = *(const bf16x8*)(d1lo + wo);
                a2[N] = MFMA16(gH[k2], wHi, a2[N]);
                a2[N] = MFMA16(gH[k2], wLo, a2[N]);
                a2[N] = MFMA16(gL[k2], wHi, a2[N]);
            }
        }
        // d2 dot: in-lane N-sum, then shfl-xor reduce over the 16 lm lanes
        float tr[4];
        #pragma unroll
        for (int r = 0; r < 4; ++r) {
            float s = 0.f;
            #pragma unroll
            for (int N = 0; N < 4; ++N)
                s = fmaf(gelu_exact(a2[N][r]), d2w[N*16 + lm], s);
            s += __shfl_xor(s, 1);
            s += __shfl_xor(s, 2);
            s += __shfl_xor(s, 4);
            s += __shfl_xor(s, 8);
            tr[r] = s;
        }
        float val = (lm == 1) ? tr[1] : (lm == 2) ? tr[2] : (lm == 3) ? tr[3] : tr[0];
        if (lm < 4)
            outp[(size_t)b*NS + s0 + w*16 + g*4 + lm] = d2b[0] + val;
    }
}

extern "C" void kernel_launch(void* const* d_in, const int* in_sizes, int n_in,
                              void* d_out, int out_size, void* d_ws, size_t ws_size,
                              hipStream_t stream) {
    const float* input = (const float*)d_in[0];
    const float* enc_w = (const float*)d_in[1];
    const float* enc_b = (const float*)d_in[2];
    const float* R_re  = (const float*)d_in[3];
    const float* R_im  = (const float*)d_in[4];
    const float* Wl_w  = (const float*)d_in[5];
    const float* Wl_b  = (const float*)d_in[6];
    const float* d1_w  = (const float*)d_in[7];
    const float* d1_b  = (const float*)d_in[8];
    const float* d2_w  = (const float*)d_in[9];
    const float* d2_b  = (const float*)d_in[10];
    float* out = (float*)d_out;

    float* ws  = (float*)d_ws;
    unsigned* hpk = (unsigned*)ws;                 // NB*NS*NC u32
    float* T   = ws  + (size_t)NB*NS*NC;           // NS*NM2 f
    float* par = T   + (size_t)NS*NM2;             // NB*NT*NC*NM2 f
    float* X   = par + (size_t)NB*NT*NC*NM2;       // NB*NM2 f
    unsigned short* Thi    = (unsigned short*)(X + (size_t)NB*NM2);
    unsigned short* Tlo    = Thi    + (size_t)NS*NM2;
    unsigned short* TThi   = Tlo    + (size_t)NS*NM2;
    unsigned short* TTlo   = TThi   + (size_t)NM2*NS;
    unsigned short* ysbThi = TTlo   + (size_t)NM2*NS;
    unsigned short* ysbTlo = ysbThi + (size_t)NB*NC*NM2;
    unsigned short* Wbhi   = ysbTlo + (size_t)NB*NC*NM2;
    unsigned short* Wblo   = Wbhi   + (size_t)NL*NC*NC;
    unsigned short* d1hi   = Wblo   + (size_t)NL*NC*NC;
    unsigned short* d1lo   = d1hi   + (size_t)NC*NC;

    hipLaunchKernelGGL(k_table, dim3(NS/256), dim3(256), 0, stream,
                       T, Thi, Tlo, TThi, TTlo);
    hipLaunchKernelGGL(k_prep, dim3((NL*NC*NC + NC*NC + 255)/256), dim3(256), 0,
                       stream, Wl_w, d1_w, Wbhi, Wblo, d1hi, d1lo);
    hipLaunchKernelGGL(k_xdft, dim3(NB), dim3(512), 0, stream, input, T, X);
    for (int l = 0; l < NL; ++l) {
        hipLaunchKernelGGL(k_mix, dim3(NB, 4), dim3(256), 0, stream,
                           par, R_re, R_im, X, enc_w, enc_b,
                           ysbThi, ysbTlo, l);
        if (l == 0) {
            hipLaunchKernelGGL((k_spec<true, false>), dim3(NT, NB), dim3(512), 0,
                               stream, input, hpk, Thi, Tlo, TThi, TTlo,
                               ysbThi, ysbTlo, Wbhi, Wblo, Wl_b,
                               d1hi, d1lo, d1_b, d2_w, d2_b, enc_w, enc_b,
                               par, out, l);
        } else if (l < NL - 1) {
            hipLaunchKernelGGL((k_spec<false, false>), dim3(NT, NB), dim3(512), 0,
                               stream, input, hpk, Thi, Tlo, TThi, TTlo,
                               ysbThi, ysbTlo, Wbhi, Wblo, Wl_b,
                               d1hi, d1lo, d1_b, d2_w, d2_b, enc_w, enc_b,
                               par, out, l);
        } else {
            hipLaunchKernelGGL((k_spec<false, true>), dim3(NT, NB), dim3(512), 0,
                               stream, input, hpk, Thi, Tlo, TThi, TTlo,
                               ysbThi, ysbTlo, Wbhi, Wblo, Wl_b,
                               d1hi, d1lo, d1_b, d2_w, d2_b, enc_w, enc_b,
                               par, out, l);
        }
    }
}